// Round 7
// baseline (2011.335 us; speedup 1.0000x reference)
//
#include <hip/hip_runtime.h>
#include <math.h>
#include <stdint.h>

#define FMW 50
#define P_IMG 2500
#define CIN 512
#define NANCH 22500
#define BATCH 16
#define PRE 512
#define POST 128
#define NCHUNK 44
#define NPAD (NCHUNK * 512)   // 22528
#define MB 192                // block px tile
#define NTIL 14               // ceil(2500/192)
#define WIN 320               // A halo window (64 + 192 + 64)

typedef __attribute__((ext_vector_type(8))) short short8;
typedef __attribute__((ext_vector_type(16))) float f32x16;

union U4S8 { uint4 u; short8 s; };

__device__ __forceinline__ unsigned short f2bf(float x) {
    unsigned u = __float_as_uint(x);
    unsigned r = u + 0x7FFFu + ((u >> 16) & 1u);
    return (unsigned short)(r >> 16);
}
__device__ __forceinline__ float bf2f(unsigned short h) {
    return __uint_as_float(((unsigned)h) << 16);
}

// ---------------- K0: prepack w1 -> bf16 hi/lo MFMA-fragment order (V2, verified) ----
// layout: [pos(9)][c(32)][NT(16)][s(2)][lane(64)][8 bf16]
__global__ void k_prepack(const float* __restrict__ w1, char* __restrict__ w1pack) {
    int t = blockIdx.x * 256 + threadIdx.x;        // 9*32*16*64 = 294912
    int l = t & 63;
    int NT = (t >> 6) & 15;
    int c = (t >> 10) & 31;
    int pos = t >> 15;
    int oc = NT * 32 + (l & 31);
    unsigned short hv[8], lv[8];
#pragma unroll
    for (int j = 0; j < 8; ++j) {
        int ci = c * 16 + (l >> 5) * 8 + j;
        float x = w1[((size_t)oc * 512 + ci) * 9 + pos];
        unsigned short h = f2bf(x);
        hv[j] = h;
        lv[j] = f2bf(x - bf2f(h));
    }
    size_t base = ((size_t)((pos * 32 + c) * 16 + NT) * 2) * 1024 + (size_t)l * 16;
    uint4 hu, lu;
    hu.x = hv[0] | ((unsigned)hv[1] << 16); hu.y = hv[2] | ((unsigned)hv[3] << 16);
    hu.z = hv[4] | ((unsigned)hv[5] << 16); hu.w = hv[6] | ((unsigned)hv[7] << 16);
    lu.x = lv[0] | ((unsigned)lv[1] << 16); lu.y = lv[2] | ((unsigned)lv[3] << 16);
    lu.z = lv[4] | ((unsigned)lv[5] << 16); lu.w = lv[6] | ((unsigned)lv[7] << 16);
    *(uint4*)(w1pack + base) = hu;
    *(uint4*)(w1pack + base + 1024) = lu;
}

// B-fragment load for tile kk into 8 NAMED uint4 registers (no arrays -> no scratch)
#define LOADB(kk, H0, H1, H2, H3, L0, L1, L2, L3)                               \
    {                                                                           \
        const char* src_ = wq + (size_t)((((kk) % 9) * 32 + (kk) / 9)) * 32768; \
        H0 = *(const uint4*)(src_);        L0 = *(const uint4*)(src_ + 1024);   \
        H1 = *(const uint4*)(src_ + 2048); L1 = *(const uint4*)(src_ + 3072);   \
        H2 = *(const uint4*)(src_ + 4096); L2 = *(const uint4*)(src_ + 5120);   \
        H3 = *(const uint4*)(src_ + 6144); L3 = *(const uint4*)(src_ + 7168);   \
    }

#define MFMA3(NT, BH, BL)                                                                     \
    {                                                                                         \
        U4S8 bh_, bl_;                                                                        \
        bh_.u = BH; bl_.u = BL;                                                               \
        _Pragma("unroll")                                                                     \
        for (int mt = 0; mt < 3; ++mt) {                                                      \
            acc[mt][NT] = __builtin_amdgcn_mfma_f32_32x32x16_bf16(ah_[mt].s, bh_.s, acc[mt][NT], 0, 0, 0); \
            acc[mt][NT] = __builtin_amdgcn_mfma_f32_32x32x16_bf16(al_[mt].s, bh_.s, acc[mt][NT], 0, 0, 0); \
            acc[mt][NT] = __builtin_amdgcn_mfma_f32_32x32x16_bf16(ah_[mt].s, bl_.s, acc[mt][NT], 0, 0, 0); \
        }                                                                                     \
    }

#define COMPUTE(kk, H0, H1, H2, H3, L0, L1, L2, L3)                       \
    {                                                                     \
        const int pos_ = (kk) % 9;                                        \
        const int dx_ = pos_ % 3 - 1;                                     \
        const int dposv_ = (pos_ / 3 - 1) * FMW + dx_;                    \
        U4S8 ah_[3], al_[3];                                              \
        const char* ap_ = Abuf + arb + dposv_ * 32;                       \
        _Pragma("unroll")                                                 \
        for (int mt = 0; mt < 3; ++mt) {                                  \
            ah_[mt].u = *(const uint4*)(ap_ + mt * 1024);                 \
            al_[mt].u = *(const uint4*)(ap_ + 10240 + mt * 1024);         \
            bool xok = (dx_ == 0) || (dx_ < 0 ? (xs[mt] > 0) : (xs[mt] < FMW - 1)); \
            if (!xok) {                                                   \
                ah_[mt].u.x = 0; ah_[mt].u.y = 0; ah_[mt].u.z = 0; ah_[mt].u.w = 0; \
                al_[mt].u.x = 0; al_[mt].u.y = 0; al_[mt].u.z = 0; al_[mt].u.w = 0; \
            }                                                             \
        }                                                                 \
        __builtin_amdgcn_s_setprio(1);                                    \
        MFMA3(0, H0, L0); MFMA3(1, H1, L1); MFMA3(2, H2, L2); MFMA3(3, H3, L3); \
        __builtin_amdgcn_s_setprio(0);                                    \
    }

#define MAYBE_STAGEA(kk)                                                  \
    {                                                                     \
        const int posA_ = (kk) % 9, cA_ = (kk) / 9;                       \
        if (posA_ == 8 && cA_ < 31) {                                     \
            asm volatile("" ::: "memory");                                \
            __builtin_amdgcn_s_barrier();                                 \
            asm volatile("" ::: "memory");                                \
            stageA(cA_ + 1);                                              \
            asm volatile("s_waitcnt lgkmcnt(0)" ::: "memory");            \
            __builtin_amdgcn_s_barrier();                                 \
            asm volatile("" ::: "memory");                                \
        }                                                                 \
    }

// ---------------- K1: MFMA conv, 8 waves, B in NAMED registers (ping-pong) -------
// block tile 192 px x 512 oc; wave (r=w>>2, q=w&3) tile 96 px x 128 oc.
// B comes straight from w1pack (fragment-order, L2-resident) into registers,
// prefetched 1 tile ahead. LDS holds only the A-window -> barriers exist ONLY at
// the once-per-9-iters A-restage. Waves free-run and de-phase within each stretch,
// overlapping A ds_reads + VALU of one wave with MFMA of the other.
__global__ __launch_bounds__(512, 2)
void k_conv_mfma(const float* __restrict__ fm, const char* __restrict__ w1pack,
                 const float* __restrict__ b1, const float* __restrict__ w2,
                 const float* __restrict__ b2, const float* __restrict__ w3,
                 const float* __restrict__ b3,
                 float* __restrict__ off_ws, unsigned long long* __restrict__ keys) {
    // phase1: A 20480 @0 (rest idle)
    // phase2: SH[128][193] f32 98816 @0  |  W[48][128] f32 24576 @98816 (= 123392)
    __shared__ __align__(16) char smem[123392];

    const int t = threadIdx.x;
    const int l = t & 63;
    const int w = t >> 6;     // 0..7
    const int r = w >> 2;     // px-row 0..1
    const int q = w & 3;      // oc-col 0..3
    const int img = blockIdx.x / NTIL;
    const int p0 = (blockIdx.x % NTIL) * MB;

    f32x16 acc[3][4];
#pragma unroll
    for (int mt = 0; mt < 3; ++mt)
#pragma unroll
        for (int nt = 0; nt < 4; ++nt)
#pragma unroll
            for (int g = 0; g < 16; ++g) acc[mt][nt][g] = 0.f;

    int xs[3];
#pragma unroll
    for (int mt = 0; mt < 3; ++mt) xs[mt] = (p0 + r * 96 + mt * 32 + (l & 31)) % FMW;

    // A layout: byte = s*10240 + px*32 + (l>>5)*16   (px in [0,320))
    const int arb = (64 + r * 96 + (l & 31)) * 32 + (l >> 5) * 16;
    const size_t img_base = (size_t)img * CIN * P_IMG;

    char* Abuf = smem;

    // stage A window for ci-chunk cc (320 px x 16 ci, hi/lo)
    auto stageA = [&](int cc) {
#pragma unroll
        for (int i = 0; i < 3; ++i) {
            int flat = i * 512 + t;          // (px, ci-quarter), 320*4 = 1280
            if (flat < 1280) {
                int qq = flat & 3;
                int pxl = flat >> 2;
                int pw = p0 - 64 + pxl;
                bool ok = (pw >= 0) && (pw < P_IMG);
                float v[4];
#pragma unroll
                for (int k = 0; k < 4; ++k)
                    v[k] = ok ? fm[img_base + (size_t)(cc * 16 + qq * 4 + k) * P_IMG + pw] : 0.f;
                unsigned short h[4], lo[4];
#pragma unroll
                for (int k = 0; k < 4; ++k) {
                    h[k] = f2bf(v[k]);
                    lo[k] = f2bf(v[k] - bf2f(h[k]));
                }
                uint2 hu, lu;
                hu.x = h[0] | ((unsigned)h[1] << 16);  hu.y = h[2] | ((unsigned)h[3] << 16);
                lu.x = lo[0] | ((unsigned)lo[1] << 16); lu.y = lo[2] | ((unsigned)lo[3] << 16);
                *(uint2*)(Abuf + pxl * 32 + qq * 8) = hu;
                *(uint2*)(Abuf + 10240 + pxl * 32 + qq * 8) = lu;
            }
        }
    };

    // this wave's B base: [pos*32+c][NT=q*4+nt][s][lane]
    const char* wq = w1pack + q * 8192 + (size_t)l * 16;

    // ping-pong B register sets (all individually named -> stay in VGPRs)
    uint4 pH0, pH1, pH2, pH3, pL0, pL1, pL2, pL3;
    uint4 oH0, oH1, oH2, oH3, oL0, oL1, oL2, oL3;

    stageA(0);
    LOADB(0, pH0, pH1, pH2, pH3, pL0, pL1, pL2, pL3);
    __syncthreads();

    for (int kp = 0; kp < 144; ++kp) {
        const int kk0 = 2 * kp;
        LOADB(kk0 + 1, oH0, oH1, oH2, oH3, oL0, oL1, oL2, oL3);
        COMPUTE(kk0, pH0, pH1, pH2, pH3, pL0, pL1, pL2, pL3);
        MAYBE_STAGEA(kk0);
        if (kp < 143) LOADB(kk0 + 2, pH0, pH1, pH2, pH3, pL0, pL1, pL2, pL3);
        COMPUTE(kk0 + 1, oH0, oH1, oH2, oH3, oL0, oL1, oL2, oL3);
        MAYBE_STAGEA(kk0 + 1);
    }

    // ---------------- fused 1x1 epilogue ----------------
    float* SH = (float*)smem;              // [128 oc][193 px]
    float* W  = (float*)(smem + 98816);    // [48][128]
    float b1v[4];
#pragma unroll
    for (int nt = 0; nt < 4; ++nt) b1v[nt] = b1[q * 128 + nt * 32 + (l & 31)];

    const int pxe = t % 192;
    const int og = t / 192;                // 0,1 active; 2 idle in dot
    const int no = (og == 0) ? 23 : 22;
    float p45[23];
#pragma unroll
    for (int m = 0; m < 23; ++m) p45[m] = 0.f;

    for (int rr = 0; rr < 4; ++rr) {
        __syncthreads();
        // stage W for oc-chunk rr (45 x 128)
#pragma unroll
        for (int i = 0; i < 12; ++i) {
            int e = i * 512 + t;
            if (e < 5760) {
                int o = e >> 7, cl = e & 127;
                W[o * 128 + cl] = (o < 9) ? w2[o * 512 + rr * 128 + cl]
                                          : w3[(o - 9) * 512 + rr * 128 + cl];
            }
        }
        // waves with q == rr write relu(acc + b1) for oc-chunk rr
        if (q == rr) {
#pragma unroll
            for (int nt = 0; nt < 4; ++nt) {
                int oc_l = nt * 32 + (l & 31);
#pragma unroll
                for (int mt = 0; mt < 3; ++mt)
#pragma unroll
                    for (int g = 0; g < 16; ++g) {
                        int row = (g & 3) + 8 * (g >> 2) + 4 * (l >> 5);
                        SH[oc_l * 193 + r * 96 + mt * 32 + row] =
                            fmaxf(acc[mt][nt][g] + b1v[nt], 0.f);
                    }
            }
        }
        __syncthreads();
        if (og < 2) {
            for (int cl = 0; cl < 128; ++cl) {
                float sv = SH[cl * 193 + pxe];
#pragma unroll
                for (int m = 0; m < 23; ++m)
                    if (m < no) p45[m] = fmaf(sv, W[(og * 23 + m) * 128 + cl], p45[m]);
            }
        }
    }

    const int pE = p0 + pxe;
    if (og < 2 && pE < P_IMG) {
        for (int m = 0; m < no; ++m) {
            int o = og * 23 + m;
            if (o < 9) {
                float z = p45[m] + b2[o];
                float s = (z >= 0.f) ? (1.f / (1.f + expf(-z)))
                                     : (expf(z) / (1.f + expf(z)));
                unsigned n = (unsigned)(pE * 9 + o);
                unsigned long long key =
                    ((unsigned long long)__float_as_uint(s) << 32) |
                    (unsigned long long)(0xFFFFFFFFu - n);
                keys[(size_t)img * NPAD + n] = key;
            } else {
                int cc = o - 9;
                off_ws[((size_t)img * P_IMG + pE) * 36 + cc] = p45[m] + b3[cc];
            }
        }
    }
}

// ---------------- K2: bitonic sort each 512-chunk descending (pad-guarded) --------
__global__ __launch_bounds__(256)
void k_sort_chunks(unsigned long long* __restrict__ keys) {
    __shared__ unsigned long long sk[512];
    const int t = threadIdx.x;
    const int img = blockIdx.x / NCHUNK;
    const int ch = blockIdx.x % NCHUNK;
    const size_t base = (size_t)img * NPAD + ch * 512;
    int a0 = ch * 512 + t, a1 = ch * 512 + t + 256;
    sk[t] = (a0 < NANCH) ? keys[base + t] : 0ull;
    sk[t + 256] = (a1 < NANCH) ? keys[base + t + 256] : 0ull;
    for (int k = 2; k <= 512; k <<= 1)
        for (int j = k >> 1; j > 0; j >>= 1) {
            __syncthreads();
            for (int i = t; i < 512; i += 256) {
                int lx = i ^ j;
                if (lx > i) {
                    unsigned long long a = sk[i], b = sk[lx];
                    bool desc = ((i & k) == 0);
                    if (desc ? (a < b) : (a > b)) { sk[i] = b; sk[lx] = a; }
                }
            }
        }
    __syncthreads();
    keys[base + t] = sk[t];
    keys[base + t + 256] = sk[t + 256];
}

// ---------------- K3: merge top-512, decode, NMS, top-128 (verified V1/V2) --------
__global__ __launch_bounds__(256)
void k_nms(const unsigned long long* __restrict__ keys,
           const float* __restrict__ off_ws, float* __restrict__ out) {
    __shared__ unsigned long long top[512];
    __shared__ unsigned long long chk[512];
    __shared__ float bx1[512], by1[512], bx2[512], by2[512], bar[512], bsc[512];
    __shared__ int keep[512];

    const int t = threadIdx.x;
    const int img = blockIdx.x;
    const size_t kbase = (size_t)img * NPAD;

    top[t] = keys[kbase + t];
    top[t + 256] = keys[kbase + t + 256];

    for (int c = 1; c < NCHUNK; ++c) {
        __syncthreads();
        chk[t] = keys[kbase + c * 512 + t];
        chk[t + 256] = keys[kbase + c * 512 + t + 256];
        __syncthreads();
        for (int i = t; i < 512; i += 256) {
            unsigned long long a = top[i], b = chk[511 - i];
            top[i] = (a > b) ? a : b;
        }
        for (int j = 256; j > 0; j >>= 1) {
            __syncthreads();
            int i = ((t & ~(j - 1)) << 1) | (t & (j - 1));
            unsigned long long a = top[i], b = top[i + j];
            if (a < b) { top[i] = b; top[i + j] = a; }
        }
    }
    __syncthreads();

    for (int i = t; i < 512; i += 256) {
        unsigned long long key = top[i];
        float s = __uint_as_float((unsigned)(key >> 32));
        unsigned id = 0xFFFFFFFFu - (unsigned)(key & 0xFFFFFFFFull);
        float x1 = 0.f, y1 = 0.f, x2 = 0.f, y2 = 0.f;
        bool valid = false;
        if (key != 0ull && id < (unsigned)NANCH) {
            int p = id / 9, a = id - p * 9;
            int gy = p / FMW, gx = p - gy * FMW;
            const double SS[3] = {32.0, 64.0, 128.0};
            const double RR[3] = {0.5, 1.0, 2.0};
            double sq = sqrt(RR[a % 3]);
            float wa32 = (float)(SS[a / 3] / sq);
            float ha32 = (float)(SS[a / 3] * sq);
            double cx = ((double)gx + 0.5) * 16.0;
            double cy = ((double)gy + 0.5) * 16.0;
            float ax1 = (float)(cx - (double)(wa32 * 0.5f));
            float ay1 = (float)(cy - (double)(ha32 * 0.5f));
            float ax2 = (float)(cx + (double)(wa32 * 0.5f));
            float ay2 = (float)(cy + (double)(ha32 * 0.5f));
            float aw = ax2 - ax1, ah2 = ay2 - ay1;
            float acx = ax1 + 0.5f * aw, acy = ay1 + 0.5f * ah2;
            const float4 off = *(const float4*)(off_ws + ((size_t)img * P_IMG + p) * 36 + a * 4);
            float px = acx + off.x * aw;
            float py = acy + off.y * ah2;
            float pw = aw * expf(off.z);
            float ph = ah2 * expf(off.w);
            x1 = fminf(fmaxf(px - 0.5f * pw, 0.f), 800.f);
            y1 = fminf(fmaxf(py - 0.5f * ph, 0.f), 800.f);
            x2 = fminf(fmaxf(px + 0.5f * pw, 0.f), 800.f);
            y2 = fminf(fmaxf(py + 0.5f * ph, 0.f), 800.f);
            float ww = x2 - x1, hh = y2 - y1;
            valid = (ww >= 1e-3f) && (hh >= 1e-3f) && (s >= 0.5f);
        }
        bx1[i] = x1; by1[i] = y1; bx2[i] = x2; by2[i] = y2;
        bar[i] = (x2 - x1) * (y2 - y1);
        bsc[i] = s;
        keep[i] = valid ? 1 : 0;
    }
    __syncthreads();

    for (int i = 0; i < PRE - 1; ++i) {
        __syncthreads();
        if (keep[i] == 0) continue;
        float xi1 = bx1[i], yi1 = by1[i], xi2 = bx2[i], yi2 = by2[i], ai = bar[i];
        for (int j = i + 1 + t; j < PRE; j += 256) {
            if (keep[j]) {
                float lx = fmaxf(xi1, bx1[j]);
                float ly = fmaxf(yi1, by1[j]);
                float rx = fminf(xi2, bx2[j]);
                float ry = fminf(yi2, by2[j]);
                float iw = fmaxf(rx - lx, 0.f);
                float ih = fmaxf(ry - ly, 0.f);
                float inter = iw * ih;
                float iou = inter / (ai + bar[j] - inter + 1e-9f);
                if (iou > 0.7f) keep[j] = 0;
            }
        }
    }
    __syncthreads();

    for (int i = t; i < 512; i += 256) {
        float m = keep[i] ? bsc[i] : -1.0f;
        unsigned u = __float_as_uint(m);
        u = (u & 0x80000000u) ? ~u : (u | 0x80000000u);
        chk[i] = ((unsigned long long)u << 32) | (unsigned long long)(511 - i);
    }
    for (int k = 2; k <= 512; k <<= 1)
        for (int j = k >> 1; j > 0; j >>= 1) {
            __syncthreads();
            for (int i = t; i < 512; i += 256) {
                int lx = i ^ j;
                if (lx > i) {
                    unsigned long long a = chk[i], b = chk[lx];
                    bool desc = ((i & k) == 0);
                    if (desc ? (a < b) : (a > b)) { chk[i] = b; chk[lx] = a; }
                }
            }
        }
    __syncthreads();

    if (t < POST) {
        unsigned long long key = chk[t];
        int slot = 511 - (int)(key & 0xFFFFFFFFull);
        float m = keep[slot] ? bsc[slot] : -1.0f;
        bool ok = (m >= 0.5f);
        float* ob = out + ((size_t)img * POST + t) * 4;
        ob[0] = ok ? bx1[slot] : 0.f;
        ob[1] = ok ? by1[slot] : 0.f;
        ob[2] = ok ? bx2[slot] : 0.f;
        ob[3] = ok ? by2[slot] : 0.f;
        out[(size_t)BATCH * POST * 4 + img * POST + t] = ok ? m : 0.f;
    }
}

// ---------------- launcher ----------------
extern "C" void kernel_launch(void* const* d_in, const int* in_sizes, int n_in,
                              void* d_out, int out_size, void* d_ws, size_t ws_size,
                              hipStream_t stream) {
    const float* fm = (const float*)d_in[0];
    const float* w1 = (const float*)d_in[1];
    const float* b1 = (const float*)d_in[2];
    const float* w2 = (const float*)d_in[3];
    const float* b2 = (const float*)d_in[4];
    const float* w3 = (const float*)d_in[5];
    const float* b3 = (const float*)d_in[6];
    float* out = (float*)d_out;

    char* ws = (char*)d_ws;
    // ws layout (18,087,936 B — identical to V2's proven footprint):
    //   [0, 0x900000)           w1pack  (9,437,184 B)
    //   [0x900000, +5,760,000)  off_ws
    //   [0xE80000, +2,883,584)  keys
    char* w1pack = ws;
    float* off_ws = (float*)(ws + 0x900000);
    unsigned long long* keys = (unsigned long long*)(ws + 0xE80000);

    k_prepack<<<1152, 256, 0, stream>>>(w1, w1pack);
    k_conv_mfma<<<BATCH * NTIL, 512, 0, stream>>>(fm, w1pack, b1, w2, b2, w3, b3, off_ws, keys);
    k_sort_chunks<<<BATCH * NCHUNK, 256, 0, stream>>>(keys);
    k_nms<<<BATCH, 256, 0, stream>>>(keys, off_ws, out);
}

// Round 8
// 1066.919 us; speedup vs baseline: 1.8852x; 1.8852x over previous
//
#include <hip/hip_runtime.h>
#include <math.h>
#include <stdint.h>

#define FMW 50
#define P_IMG 2500
#define CIN 512
#define NANCH 22500
#define BATCH 16
#define PRE 512
#define POST 128
#define NCHUNK 44
#define NPAD (NCHUNK * 512)   // 22528
#define MB 192                // block px tile
#define NTIL 14               // ceil(2500/192)
#define WIN 320               // A halo window (64 + 192 + 64)

typedef __attribute__((ext_vector_type(8))) short short8;
typedef __attribute__((ext_vector_type(16))) float f32x16;

union U4S8 { uint4 u; short8 s; };

__device__ __forceinline__ unsigned short f2bf(float x) {
    unsigned u = __float_as_uint(x);
    unsigned r = u + 0x7FFFu + ((u >> 16) & 1u);
    return (unsigned short)(r >> 16);
}
__device__ __forceinline__ float bf2f(unsigned short h) {
    return __uint_as_float(((unsigned)h) << 16);
}

__device__ __forceinline__ void gload_lds16(const void* g, void* l) {
    __builtin_amdgcn_global_load_lds(
        (const __attribute__((address_space(1))) void*)g,
        (__attribute__((address_space(3))) void*)l, 16, 0, 0);
}

// ---------------- K0: prepack w1 -> bf16 hi/lo MFMA-fragment order (V2, verified) ----
// layout: [pos(9)][c(32)][NT(16)][s(2)][lane(64)][8 bf16]
__global__ void k_prepack(const float* __restrict__ w1, char* __restrict__ w1pack) {
    int t = blockIdx.x * 256 + threadIdx.x;        // 9*32*16*64 = 294912
    int l = t & 63;
    int NT = (t >> 6) & 15;
    int c = (t >> 10) & 31;
    int pos = t >> 15;
    int oc = NT * 32 + (l & 31);
    unsigned short hv[8], lv[8];
#pragma unroll
    for (int j = 0; j < 8; ++j) {
        int ci = c * 16 + (l >> 5) * 8 + j;
        float x = w1[((size_t)oc * 512 + ci) * 9 + pos];
        unsigned short h = f2bf(x);
        hv[j] = h;
        lv[j] = f2bf(x - bf2f(h));
    }
    size_t base = ((size_t)((pos * 32 + c) * 16 + NT) * 2) * 1024 + (size_t)l * 16;
    uint4 hu, lu;
    hu.x = hv[0] | ((unsigned)hv[1] << 16); hu.y = hv[2] | ((unsigned)hv[3] << 16);
    hu.z = hv[4] | ((unsigned)hv[5] << 16); hu.w = hv[6] | ((unsigned)hv[7] << 16);
    lu.x = lv[0] | ((unsigned)lv[1] << 16); lu.y = lv[2] | ((unsigned)lv[3] << 16);
    lu.z = lv[4] | ((unsigned)lv[5] << 16); lu.w = lv[6] | ((unsigned)lv[7] << 16);
    *(uint4*)(w1pack + base) = hu;
    *(uint4*)(w1pack + base + 1024) = lu;
}

// ---------------- K1: MFMA conv, 8 waves, 2/SIMD, B dbuf via global_load_lds ------
// (exact R1 structure — proven 804 µs / MfmaUtil 33%)
__global__ __launch_bounds__(512, 2)
void k_conv_mfma(const float* __restrict__ fm, const char* __restrict__ w1pack,
                 const float* __restrict__ b1, const float* __restrict__ w2,
                 const float* __restrict__ b2, const float* __restrict__ w3,
                 const float* __restrict__ b3,
                 float* __restrict__ off_ws, unsigned long long* __restrict__ keys) {
    // phase1: A-window 20480 B @0  |  Bbuf0 32768 @20480  |  Bbuf1 32768 @53248
    // phase2: SH[128][193] f32 98816 @0  |  W[48][128] f32 24576 @98816
    __shared__ __align__(16) char smem[123392];

    const int t = threadIdx.x;
    const int l = t & 63;
    const int w = t >> 6;     // 0..7
    const int r = w >> 2;     // px-row 0..1
    const int q = w & 3;      // oc-col 0..3
    const int img = blockIdx.x / NTIL;
    const int p0 = (blockIdx.x % NTIL) * MB;

    f32x16 acc[3][4];
#pragma unroll
    for (int mt = 0; mt < 3; ++mt)
#pragma unroll
        for (int nt = 0; nt < 4; ++nt)
#pragma unroll
            for (int g = 0; g < 16; ++g) acc[mt][nt][g] = 0.f;

    int xs[3];
#pragma unroll
    for (int mt = 0; mt < 3; ++mt) xs[mt] = (p0 + r * 96 + mt * 32 + (l & 31)) % FMW;

    // A layout: byte = s*10240 + px*32 + (l>>5)*16 + j*2   (px in [0,320))
    const int arb = (64 + r * 96 + (l & 31)) * 32 + (l >> 5) * 16;
    const size_t img_base = (size_t)img * CIN * P_IMG;
    const int DPOS[9] = {-51, -50, -49, -1, 0, 1, 49, 50, 51};

    char* Abuf = smem;
    char* Bb0 = smem + 20480;
    char* Bb1 = smem + 53248;

    // stage A window for ci-chunk cc (320 px x 16 ci, hi/lo)
    auto stageA = [&](int cc) {
#pragma unroll
        for (int i = 0; i < 3; ++i) {
            int flat = i * 512 + t;          // (px, ci-quarter), 320*4 = 1280
            if (flat < 1280) {
                int qq = flat & 3;
                int pxl = flat >> 2;
                int pw = p0 - 64 + pxl;
                bool ok = (pw >= 0) && (pw < P_IMG);
                float v[4];
#pragma unroll
                for (int k = 0; k < 4; ++k)
                    v[k] = ok ? fm[img_base + (size_t)(cc * 16 + qq * 4 + k) * P_IMG + pw] : 0.f;
                unsigned short h[4], lo[4];
#pragma unroll
                for (int k = 0; k < 4; ++k) {
                    h[k] = f2bf(v[k]);
                    lo[k] = f2bf(v[k] - bf2f(h[k]));
                }
                uint2 hu, lu;
                hu.x = h[0] | ((unsigned)h[1] << 16);  hu.y = h[2] | ((unsigned)h[3] << 16);
                lu.x = lo[0] | ((unsigned)lo[1] << 16); lu.y = lo[2] | ((unsigned)lo[3] << 16);
                *(uint2*)(Abuf + pxl * 32 + qq * 8) = hu;
                *(uint2*)(Abuf + 10240 + pxl * 32 + qq * 8) = lu;
            }
        }
    };

    // async-stage B tile for iteration kk into buffer (kk&1): 32 KB, 4 chunks/wave
    auto stageB = [&](int kk) {
        int c = kk / 9, pos = kk % 9;
        const char* src = w1pack + (size_t)(pos * 32 + c) * 32768;
        char* dst = (kk & 1) ? Bb1 : Bb0;
#pragma unroll
        for (int j = 0; j < 4; ++j) {
            int chunk = w * 4 + j;
            gload_lds16(src + chunk * 1024 + l * 16, dst + chunk * 1024);
        }
    };

    stageB(0);
    stageA(0);
    __syncthreads();

    for (int kk = 0; kk < 288; ++kk) {
        const int c = kk / 9, pos = kk % 9;
        if (kk + 1 < 288) stageB(kk + 1);

        // ---- compute (c, pos) from Abuf + Bbuf[kk&1] ----
        const int dpos = DPOS[pos];
        const int dx = pos % 3 - 1;
        U4S8 ah[3], al[3];
        const char* ap = Abuf + arb + dpos * 32;
#pragma unroll
        for (int mt = 0; mt < 3; ++mt) {
            ah[mt].u = *(const uint4*)(ap + mt * 1024);
            al[mt].u = *(const uint4*)(ap + 10240 + mt * 1024);
            bool xok = (dx == 0) || (dx < 0 ? (xs[mt] > 0) : (xs[mt] < FMW - 1));
            if (!xok) {
                ah[mt].u.x = 0; ah[mt].u.y = 0; ah[mt].u.z = 0; ah[mt].u.w = 0;
                al[mt].u.x = 0; al[mt].u.y = 0; al[mt].u.z = 0; al[mt].u.w = 0;
            }
        }
        const char* bp = ((kk & 1) ? Bb1 : Bb0) + q * 8192 + l * 16;
#pragma unroll
        for (int nt = 0; nt < 4; ++nt) {
            U4S8 bh, bl;
            bh.u = *(const uint4*)(bp + nt * 2048);
            bl.u = *(const uint4*)(bp + nt * 2048 + 1024);
#pragma unroll
            for (int mt = 0; mt < 3; ++mt) {
                acc[mt][nt] = __builtin_amdgcn_mfma_f32_32x32x16_bf16(ah[mt].s, bh.s, acc[mt][nt], 0, 0, 0);
                acc[mt][nt] = __builtin_amdgcn_mfma_f32_32x32x16_bf16(al[mt].s, bh.s, acc[mt][nt], 0, 0, 0);
                acc[mt][nt] = __builtin_amdgcn_mfma_f32_32x32x16_bf16(ah[mt].s, bl.s, acc[mt][nt], 0, 0, 0);
            }
        }

        if (pos == 8 && c < 31) {
            __syncthreads();      // everyone done reading Abuf for chunk c
            stageA(c + 1);
        }
        __syncthreads();          // drains stageB(kk+1) (vmcnt) + A writes
    }

    // ---------------- fused 1x1 epilogue ----------------
    float* SH = (float*)smem;              // [128 oc][193 px]
    float* W  = (float*)(smem + 98816);    // [48][128]
    float b1v[4];
#pragma unroll
    for (int nt = 0; nt < 4; ++nt) b1v[nt] = b1[q * 128 + nt * 32 + (l & 31)];

    const int pxe = t % 192;
    const int og = t / 192;                // 0,1 active; 2 idle in dot
    const int no = (og == 0) ? 23 : 22;
    float p45[23];
#pragma unroll
    for (int m = 0; m < 23; ++m) p45[m] = 0.f;

    for (int rr = 0; rr < 4; ++rr) {
        __syncthreads();
        // stage W for oc-chunk rr (45 x 128)
#pragma unroll
        for (int i = 0; i < 12; ++i) {
            int e = i * 512 + t;
            if (e < 5760) {
                int o = e >> 7, cl = e & 127;
                W[o * 128 + cl] = (o < 9) ? w2[o * 512 + rr * 128 + cl]
                                          : w3[(o - 9) * 512 + rr * 128 + cl];
            }
        }
        // waves with q == rr write relu(acc + b1) for oc-chunk rr
        if (q == rr) {
#pragma unroll
            for (int nt = 0; nt < 4; ++nt) {
                int oc_l = nt * 32 + (l & 31);
#pragma unroll
                for (int mt = 0; mt < 3; ++mt)
#pragma unroll
                    for (int g = 0; g < 16; ++g) {
                        int row = (g & 3) + 8 * (g >> 2) + 4 * (l >> 5);
                        SH[oc_l * 193 + r * 96 + mt * 32 + row] =
                            fmaxf(acc[mt][nt][g] + b1v[nt], 0.f);
                    }
            }
        }
        __syncthreads();
        if (og < 2) {
            for (int cl = 0; cl < 128; ++cl) {
                float sv = SH[cl * 193 + pxe];
#pragma unroll
                for (int m = 0; m < 23; ++m)
                    if (m < no) p45[m] = fmaf(sv, W[(og * 23 + m) * 128 + cl], p45[m]);
            }
        }
    }

    const int pE = p0 + pxe;
    if (og < 2 && pE < P_IMG) {
        for (int m = 0; m < no; ++m) {
            int o = og * 23 + m;
            if (o < 9) {
                float z = p45[m] + b2[o];
                float s = (z >= 0.f) ? (1.f / (1.f + expf(-z)))
                                     : (expf(z) / (1.f + expf(z)));
                unsigned n = (unsigned)(pE * 9 + o);
                unsigned long long key =
                    ((unsigned long long)__float_as_uint(s) << 32) |
                    (unsigned long long)(0xFFFFFFFFu - n);
                keys[(size_t)img * NPAD + n] = key;
            } else {
                int cc = o - 9;
                off_ws[((size_t)img * P_IMG + pE) * 36 + cc] = p45[m] + b3[cc];
            }
        }
    }
}

// ---------------- K2: bitonic sort each 512-chunk descending (pad-guarded) --------
__global__ __launch_bounds__(256)
void k_sort_chunks(unsigned long long* __restrict__ keys) {
    __shared__ unsigned long long sk[512];
    const int t = threadIdx.x;
    const int img = blockIdx.x / NCHUNK;
    const int ch = blockIdx.x % NCHUNK;
    const size_t base = (size_t)img * NPAD + ch * 512;
    int a0 = ch * 512 + t, a1 = ch * 512 + t + 256;
    sk[t] = (a0 < NANCH) ? keys[base + t] : 0ull;
    sk[t + 256] = (a1 < NANCH) ? keys[base + t + 256] : 0ull;
    for (int k = 2; k <= 512; k <<= 1)
        for (int j = k >> 1; j > 0; j >>= 1) {
            __syncthreads();
            for (int i = t; i < 512; i += 256) {
                int lx = i ^ j;
                if (lx > i) {
                    unsigned long long a = sk[i], b = sk[lx];
                    bool desc = ((i & k) == 0);
                    if (desc ? (a < b) : (a > b)) { sk[i] = b; sk[lx] = a; }
                }
            }
        }
    __syncthreads();
    keys[base + t] = sk[t];
    keys[base + t + 256] = sk[t + 256];
}

// ---------------- K3: merge top-512, decode, BITMASK NMS, top-128 ----------------
// NMS rewritten: parallel 512x512 suppression-bit matrix (broadcast LDS reads),
// then a single-wave serial sweep with zero barriers (replaces 511 __syncthreads).
__global__ __launch_bounds__(256)
void k_nms(const unsigned long long* __restrict__ keys,
           const float* __restrict__ off_ws, float* __restrict__ out) {
    __shared__ unsigned long long top[512];
    __shared__ unsigned long long chk[512];
    __shared__ float bx1[512], by1[512], bx2[512], by2[512], bar[512], bsc[512];
    __shared__ int keep[512];
    __shared__ unsigned long long sup[512][9];   // 8 words + 1 pad (bank spread)
    __shared__ unsigned long long kmask[8];

    const int t = threadIdx.x;
    const int img = blockIdx.x;
    const size_t kbase = (size_t)img * NPAD;

    top[t] = keys[kbase + t];
    top[t + 256] = keys[kbase + t + 256];

    for (int c = 1; c < NCHUNK; ++c) {
        __syncthreads();
        chk[t] = keys[kbase + c * 512 + t];
        chk[t + 256] = keys[kbase + c * 512 + t + 256];
        __syncthreads();
        for (int i = t; i < 512; i += 256) {
            unsigned long long a = top[i], b = chk[511 - i];
            top[i] = (a > b) ? a : b;
        }
        for (int j = 256; j > 0; j >>= 1) {
            __syncthreads();
            int i = ((t & ~(j - 1)) << 1) | (t & (j - 1));
            unsigned long long a = top[i], b = top[i + j];
            if (a < b) { top[i] = b; top[i + j] = a; }
        }
    }
    __syncthreads();

    for (int i = t; i < 512; i += 256) {
        unsigned long long key = top[i];
        float s = __uint_as_float((unsigned)(key >> 32));
        unsigned id = 0xFFFFFFFFu - (unsigned)(key & 0xFFFFFFFFull);
        float x1 = 0.f, y1 = 0.f, x2 = 0.f, y2 = 0.f;
        bool valid = false;
        if (key != 0ull && id < (unsigned)NANCH) {
            int p = id / 9, a = id - p * 9;
            int gy = p / FMW, gx = p - gy * FMW;
            const double SS[3] = {32.0, 64.0, 128.0};
            const double RR[3] = {0.5, 1.0, 2.0};
            double sq = sqrt(RR[a % 3]);
            float wa32 = (float)(SS[a / 3] / sq);
            float ha32 = (float)(SS[a / 3] * sq);
            double cx = ((double)gx + 0.5) * 16.0;
            double cy = ((double)gy + 0.5) * 16.0;
            float ax1 = (float)(cx - (double)(wa32 * 0.5f));
            float ay1 = (float)(cy - (double)(ha32 * 0.5f));
            float ax2 = (float)(cx + (double)(wa32 * 0.5f));
            float ay2 = (float)(cy + (double)(ha32 * 0.5f));
            float aw = ax2 - ax1, ah2 = ay2 - ay1;
            float acx = ax1 + 0.5f * aw, acy = ay1 + 0.5f * ah2;
            const float4 off = *(const float4*)(off_ws + ((size_t)img * P_IMG + p) * 36 + a * 4);
            float px = acx + off.x * aw;
            float py = acy + off.y * ah2;
            float pw = aw * expf(off.z);
            float ph = ah2 * expf(off.w);
            x1 = fminf(fmaxf(px - 0.5f * pw, 0.f), 800.f);
            y1 = fminf(fmaxf(py - 0.5f * ph, 0.f), 800.f);
            x2 = fminf(fmaxf(px + 0.5f * pw, 0.f), 800.f);
            y2 = fminf(fmaxf(py + 0.5f * ph, 0.f), 800.f);
            float ww = x2 - x1, hh = y2 - y1;
            valid = (ww >= 1e-3f) && (hh >= 1e-3f) && (s >= 0.5f);
        }
        bx1[i] = x1; by1[i] = y1; bx2[i] = x2; by2[i] = y2;
        bar[i] = (x2 - x1) * (y2 - y1);
        bsc[i] = s;
        keep[i] = valid ? 1 : 0;
    }
    __syncthreads();

    // ---- build suppression bit-matrix: sup[i] bit j = (iou>0.7) && (j>i) ----
    // all lanes of a wave process the same j simultaneously -> LDS broadcast reads
    for (int i = t; i < 512; i += 256) {
        float xi1 = bx1[i], yi1 = by1[i], xi2 = bx2[i], yi2 = by2[i], ai = bar[i];
#pragma unroll
        for (int wd = 0; wd < 8; ++wd) {
            unsigned long long bits = 0ull;
            for (int b = 0; b < 64; ++b) {
                int j = wd * 64 + b;
                float lx = fmaxf(xi1, bx1[j]);
                float ly = fmaxf(yi1, by1[j]);
                float rx = fminf(xi2, bx2[j]);
                float ry = fminf(yi2, by2[j]);
                float iw = fmaxf(rx - lx, 0.f);
                float ih = fmaxf(ry - ly, 0.f);
                float inter = iw * ih;
                float iou = inter / (ai + bar[j] - inter + 1e-9f);
                if ((iou > 0.7f) && (j > i)) bits |= (1ull << b);
            }
            sup[i][wd] = bits;
        }
    }
    // pack initial keep mask (8 threads x 64 flags)
    if (t < 8) {
        unsigned long long m = 0ull;
#pragma unroll
        for (int b = 0; b < 64; ++b)
            if (keep[t * 64 + b]) m |= (1ull << b);
        kmask[t] = m;
    }
    __syncthreads();

    // ---- serial greedy sweep: one wave, zero barriers ----
    if (t < 64) {
        unsigned long long m = (t < 8) ? kmask[t] : 0ull;
        for (int i = 0; i < 512; ++i) {
            unsigned long long mw = __shfl(m, i >> 6);      // broadcast word i/64
            if ((mw >> (i & 63)) & 1ull) {                  // i still kept (uniform)
                if (t < 8) m &= ~sup[i][t];
            }
        }
        if (t < 8) kmask[t] = m;
    }
    __syncthreads();
    for (int i = t; i < 512; i += 256)
        keep[i] = (int)((kmask[i >> 6] >> (i & 63)) & 1ull);
    __syncthreads();

    for (int i = t; i < 512; i += 256) {
        float m = keep[i] ? bsc[i] : -1.0f;
        unsigned u = __float_as_uint(m);
        u = (u & 0x80000000u) ? ~u : (u | 0x80000000u);
        chk[i] = ((unsigned long long)u << 32) | (unsigned long long)(511 - i);
    }
    for (int k = 2; k <= 512; k <<= 1)
        for (int j = k >> 1; j > 0; j >>= 1) {
            __syncthreads();
            for (int i = t; i < 512; i += 256) {
                int lx = i ^ j;
                if (lx > i) {
                    unsigned long long a = chk[i], b = chk[lx];
                    bool desc = ((i & k) == 0);
                    if (desc ? (a < b) : (a > b)) { chk[i] = b; chk[lx] = a; }
                }
            }
        }
    __syncthreads();

    if (t < POST) {
        unsigned long long key = chk[t];
        int slot = 511 - (int)(key & 0xFFFFFFFFull);
        float m = keep[slot] ? bsc[slot] : -1.0f;
        bool ok = (m >= 0.5f);
        float* ob = out + ((size_t)img * POST + t) * 4;
        ob[0] = ok ? bx1[slot] : 0.f;
        ob[1] = ok ? by1[slot] : 0.f;
        ob[2] = ok ? bx2[slot] : 0.f;
        ob[3] = ok ? by2[slot] : 0.f;
        out[(size_t)BATCH * POST * 4 + img * POST + t] = ok ? m : 0.f;
    }
}

// ---------------- launcher ----------------
extern "C" void kernel_launch(void* const* d_in, const int* in_sizes, int n_in,
                              void* d_out, int out_size, void* d_ws, size_t ws_size,
                              hipStream_t stream) {
    const float* fm = (const float*)d_in[0];
    const float* w1 = (const float*)d_in[1];
    const float* b1 = (const float*)d_in[2];
    const float* w2 = (const float*)d_in[3];
    const float* b2 = (const float*)d_in[4];
    const float* w3 = (const float*)d_in[5];
    const float* b3 = (const float*)d_in[6];
    float* out = (float*)d_out;

    char* ws = (char*)d_ws;
    // ws layout (18,087,936 B — identical to V2's proven footprint):
    //   [0, 0x900000)           w1pack  (9,437,184 B)
    //   [0x900000, +5,760,000)  off_ws
    //   [0xE80000, +2,883,584)  keys
    char* w1pack = ws;
    float* off_ws = (float*)(ws + 0x900000);
    unsigned long long* keys = (unsigned long long*)(ws + 0xE80000);

    k_prepack<<<1152, 256, 0, stream>>>(w1, w1pack);
    k_conv_mfma<<<BATCH * NTIL, 512, 0, stream>>>(fm, w1pack, b1, w2, b2, w3, b3, off_ws, keys);
    k_sort_chunks<<<BATCH * NCHUNK, 256, 0, stream>>>(keys);
    k_nms<<<BATCH, 256, 0, stream>>>(keys, off_ws, out);
}

// Round 9
// 1038.430 us; speedup vs baseline: 1.9369x; 1.0274x over previous
//
#include <hip/hip_runtime.h>
#include <math.h>
#include <stdint.h>

#define FMW 50
#define P_IMG 2500
#define CIN 512
#define NANCH 22500
#define BATCH 16
#define PRE 512
#define POST 128
#define NCH2 11               // 11 spans of 2048
#define CHSZ 2048
#define NPAD (NCH2 * CHSZ)    // 22528
#define MB 192                // block px tile
#define NTIL 14               // ceil(2500/192)
#define WIN 320               // A halo window (64 + 192 + 64)

typedef __attribute__((ext_vector_type(8))) short short8;
typedef __attribute__((ext_vector_type(16))) float f32x16;

union U4S8 { uint4 u; short8 s; };

__device__ __forceinline__ unsigned short f2bf(float x) {
    unsigned u = __float_as_uint(x);
    unsigned r = u + 0x7FFFu + ((u >> 16) & 1u);
    return (unsigned short)(r >> 16);
}
__device__ __forceinline__ float bf2f(unsigned short h) {
    return __uint_as_float(((unsigned)h) << 16);
}

__device__ __forceinline__ void gload_lds16(const void* g, void* l) {
    __builtin_amdgcn_global_load_lds(
        (const __attribute__((address_space(1))) void*)g,
        (__attribute__((address_space(3))) void*)l, 16, 0, 0);
}

// ---------------- K0: prepack w1 -> bf16 hi/lo MFMA-fragment order (V2, verified) ----
// layout: [pos(9)][c(32)][NT(16)][s(2)][lane(64)][8 bf16]
__global__ void k_prepack(const float* __restrict__ w1, char* __restrict__ w1pack) {
    int t = blockIdx.x * 256 + threadIdx.x;        // 9*32*16*64 = 294912
    int l = t & 63;
    int NT = (t >> 6) & 15;
    int c = (t >> 10) & 31;
    int pos = t >> 15;
    int oc = NT * 32 + (l & 31);
    unsigned short hv[8], lv[8];
#pragma unroll
    for (int j = 0; j < 8; ++j) {
        int ci = c * 16 + (l >> 5) * 8 + j;
        float x = w1[((size_t)oc * 512 + ci) * 9 + pos];
        unsigned short h = f2bf(x);
        hv[j] = h;
        lv[j] = f2bf(x - bf2f(h));
    }
    size_t base = ((size_t)((pos * 32 + c) * 16 + NT) * 2) * 1024 + (size_t)l * 16;
    uint4 hu, lu;
    hu.x = hv[0] | ((unsigned)hv[1] << 16); hu.y = hv[2] | ((unsigned)hv[3] << 16);
    hu.z = hv[4] | ((unsigned)hv[5] << 16); hu.w = hv[6] | ((unsigned)hv[7] << 16);
    lu.x = lv[0] | ((unsigned)lv[1] << 16); lu.y = lv[2] | ((unsigned)lv[3] << 16);
    lu.z = lv[4] | ((unsigned)lv[5] << 16); lu.w = lv[6] | ((unsigned)lv[7] << 16);
    *(uint4*)(w1pack + base) = hu;
    *(uint4*)(w1pack + base + 1024) = lu;
}

// ---------------- K1: MFMA conv, 8 waves, 2/SIMD, B dbuf via global_load_lds ------
// (exact R1 structure — proven ~796 µs / MfmaUtil 33%)
__global__ __launch_bounds__(512, 2)
void k_conv_mfma(const float* __restrict__ fm, const char* __restrict__ w1pack,
                 const float* __restrict__ b1, const float* __restrict__ w2,
                 const float* __restrict__ b2, const float* __restrict__ w3,
                 const float* __restrict__ b3,
                 float* __restrict__ off_ws, unsigned long long* __restrict__ keys) {
    // phase1: A-window 20480 B @0  |  Bbuf0 32768 @20480  |  Bbuf1 32768 @53248
    // phase2: SH[128][193] f32 98816 @0  |  W[48][128] f32 24576 @98816
    __shared__ __align__(16) char smem[123392];

    const int t = threadIdx.x;
    const int l = t & 63;
    const int w = t >> 6;     // 0..7
    const int r = w >> 2;     // px-row 0..1
    const int q = w & 3;      // oc-col 0..3
    const int img = blockIdx.x / NTIL;
    const int p0 = (blockIdx.x % NTIL) * MB;

    f32x16 acc[3][4];
#pragma unroll
    for (int mt = 0; mt < 3; ++mt)
#pragma unroll
        for (int nt = 0; nt < 4; ++nt)
#pragma unroll
            for (int g = 0; g < 16; ++g) acc[mt][nt][g] = 0.f;

    int xs[3];
#pragma unroll
    for (int mt = 0; mt < 3; ++mt) xs[mt] = (p0 + r * 96 + mt * 32 + (l & 31)) % FMW;

    // A layout: byte = s*10240 + px*32 + (l>>5)*16 + j*2   (px in [0,320))
    const int arb = (64 + r * 96 + (l & 31)) * 32 + (l >> 5) * 16;
    const size_t img_base = (size_t)img * CIN * P_IMG;
    const int DPOS[9] = {-51, -50, -49, -1, 0, 1, 49, 50, 51};

    char* Abuf = smem;
    char* Bb0 = smem + 20480;
    char* Bb1 = smem + 53248;

    // stage A window for ci-chunk cc (320 px x 16 ci, hi/lo)
    auto stageA = [&](int cc) {
#pragma unroll
        for (int i = 0; i < 3; ++i) {
            int flat = i * 512 + t;          // (px, ci-quarter), 320*4 = 1280
            if (flat < 1280) {
                int qq = flat & 3;
                int pxl = flat >> 2;
                int pw = p0 - 64 + pxl;
                bool ok = (pw >= 0) && (pw < P_IMG);
                float v[4];
#pragma unroll
                for (int k = 0; k < 4; ++k)
                    v[k] = ok ? fm[img_base + (size_t)(cc * 16 + qq * 4 + k) * P_IMG + pw] : 0.f;
                unsigned short h[4], lo[4];
#pragma unroll
                for (int k = 0; k < 4; ++k) {
                    h[k] = f2bf(v[k]);
                    lo[k] = f2bf(v[k] - bf2f(h[k]));
                }
                uint2 hu, lu;
                hu.x = h[0] | ((unsigned)h[1] << 16);  hu.y = h[2] | ((unsigned)h[3] << 16);
                lu.x = lo[0] | ((unsigned)lo[1] << 16); lu.y = lo[2] | ((unsigned)lo[3] << 16);
                *(uint2*)(Abuf + pxl * 32 + qq * 8) = hu;
                *(uint2*)(Abuf + 10240 + pxl * 32 + qq * 8) = lu;
            }
        }
    };

    // async-stage B tile for iteration kk into buffer (kk&1): 32 KB, 4 chunks/wave
    auto stageB = [&](int kk) {
        int c = kk / 9, pos = kk % 9;
        const char* src = w1pack + (size_t)(pos * 32 + c) * 32768;
        char* dst = (kk & 1) ? Bb1 : Bb0;
#pragma unroll
        for (int j = 0; j < 4; ++j) {
            int chunk = w * 4 + j;
            gload_lds16(src + chunk * 1024 + l * 16, dst + chunk * 1024);
        }
    };

    stageB(0);
    stageA(0);
    __syncthreads();

    for (int kk = 0; kk < 288; ++kk) {
        const int c = kk / 9, pos = kk % 9;
        if (kk + 1 < 288) stageB(kk + 1);

        // ---- compute (c, pos) from Abuf + Bbuf[kk&1] ----
        const int dpos = DPOS[pos];
        const int dx = pos % 3 - 1;
        U4S8 ah[3], al[3];
        const char* ap = Abuf + arb + dpos * 32;
#pragma unroll
        for (int mt = 0; mt < 3; ++mt) {
            ah[mt].u = *(const uint4*)(ap + mt * 1024);
            al[mt].u = *(const uint4*)(ap + 10240 + mt * 1024);
            bool xok = (dx == 0) || (dx < 0 ? (xs[mt] > 0) : (xs[mt] < FMW - 1));
            if (!xok) {
                ah[mt].u.x = 0; ah[mt].u.y = 0; ah[mt].u.z = 0; ah[mt].u.w = 0;
                al[mt].u.x = 0; al[mt].u.y = 0; al[mt].u.z = 0; al[mt].u.w = 0;
            }
        }
        const char* bp = ((kk & 1) ? Bb1 : Bb0) + q * 8192 + l * 16;
#pragma unroll
        for (int nt = 0; nt < 4; ++nt) {
            U4S8 bh, bl;
            bh.u = *(const uint4*)(bp + nt * 2048);
            bl.u = *(const uint4*)(bp + nt * 2048 + 1024);
#pragma unroll
            for (int mt = 0; mt < 3; ++mt) {
                acc[mt][nt] = __builtin_amdgcn_mfma_f32_32x32x16_bf16(ah[mt].s, bh.s, acc[mt][nt], 0, 0, 0);
                acc[mt][nt] = __builtin_amdgcn_mfma_f32_32x32x16_bf16(al[mt].s, bh.s, acc[mt][nt], 0, 0, 0);
                acc[mt][nt] = __builtin_amdgcn_mfma_f32_32x32x16_bf16(ah[mt].s, bl.s, acc[mt][nt], 0, 0, 0);
            }
        }

        if (pos == 8 && c < 31) {
            __syncthreads();      // everyone done reading Abuf for chunk c
            stageA(c + 1);
        }
        __syncthreads();          // drains stageB(kk+1) (vmcnt) + A writes
    }

    // ---------------- fused 1x1 epilogue ----------------
    float* SH = (float*)smem;              // [128 oc][193 px]
    float* W  = (float*)(smem + 98816);    // [48][128]
    float b1v[4];
#pragma unroll
    for (int nt = 0; nt < 4; ++nt) b1v[nt] = b1[q * 128 + nt * 32 + (l & 31)];

    const int pxe = t % 192;
    const int og = t / 192;                // 0,1 active; 2 idle in dot
    const int no = (og == 0) ? 23 : 22;
    float p45[23];
#pragma unroll
    for (int m = 0; m < 23; ++m) p45[m] = 0.f;

    for (int rr = 0; rr < 4; ++rr) {
        __syncthreads();
        // stage W for oc-chunk rr (45 x 128)
#pragma unroll
        for (int i = 0; i < 12; ++i) {
            int e = i * 512 + t;
            if (e < 5760) {
                int o = e >> 7, cl = e & 127;
                W[o * 128 + cl] = (o < 9) ? w2[o * 512 + rr * 128 + cl]
                                          : w3[(o - 9) * 512 + rr * 128 + cl];
            }
        }
        // waves with q == rr write relu(acc + b1) for oc-chunk rr
        if (q == rr) {
#pragma unroll
            for (int nt = 0; nt < 4; ++nt) {
                int oc_l = nt * 32 + (l & 31);
#pragma unroll
                for (int mt = 0; mt < 3; ++mt)
#pragma unroll
                    for (int g = 0; g < 16; ++g) {
                        int row = (g & 3) + 8 * (g >> 2) + 4 * (l >> 5);
                        SH[oc_l * 193 + r * 96 + mt * 32 + row] =
                            fmaxf(acc[mt][nt][g] + b1v[nt], 0.f);
                    }
            }
        }
        __syncthreads();
        if (og < 2) {
            for (int cl = 0; cl < 128; ++cl) {
                float sv = SH[cl * 193 + pxe];
#pragma unroll
                for (int m = 0; m < 23; ++m)
                    if (m < no) p45[m] = fmaf(sv, W[(og * 23 + m) * 128 + cl], p45[m]);
            }
        }
    }

    const int pE = p0 + pxe;
    if (og < 2 && pE < P_IMG) {
        for (int m = 0; m < no; ++m) {
            int o = og * 23 + m;
            if (o < 9) {
                float z = p45[m] + b2[o];
                float s = (z >= 0.f) ? (1.f / (1.f + expf(-z)))
                                     : (expf(z) / (1.f + expf(z)));
                unsigned n = (unsigned)(pE * 9 + o);
                unsigned long long key =
                    ((unsigned long long)__float_as_uint(s) << 32) |
                    (unsigned long long)(0xFFFFFFFFu - n);
                keys[(size_t)img * NPAD + n] = key;
            } else {
                int cc = o - 9;
                off_ws[((size_t)img * P_IMG + pE) * 36 + cc] = p45[m] + b3[cc];
            }
        }
    }
}

// ---------------- K2: bitonic sort each 2048-span descending (pad-guarded) --------
// 176 blocks x 512 threads, 16KB LDS. Span's top-512 = its first 512 entries ->
// k_nms needs only 10 merge iterations (was 43).
__global__ __launch_bounds__(512)
void k_sort_chunks(unsigned long long* __restrict__ keys) {
    __shared__ unsigned long long sk[CHSZ];
    const int t = threadIdx.x;
    const int img = blockIdx.x / NCH2;
    const int ch = blockIdx.x % NCH2;
    const size_t base = (size_t)img * NPAD + (size_t)ch * CHSZ;
#pragma unroll
    for (int i = 0; i < 4; ++i) {
        int idx = i * 512 + t;
        int a = ch * CHSZ + idx;
        sk[idx] = (a < NANCH) ? keys[base + idx] : 0ull;
    }
    for (int k = 2; k <= CHSZ; k <<= 1)
        for (int j = k >> 1; j > 0; j >>= 1) {
            __syncthreads();
#pragma unroll
            for (int ii = 0; ii < 4; ++ii) {
                int i = ii * 512 + t;
                int lx = i ^ j;
                if (lx > i) {
                    unsigned long long a = sk[i], b = sk[lx];
                    bool desc = ((i & k) == 0);
                    if (desc ? (a < b) : (a > b)) { sk[i] = b; sk[lx] = a; }
                }
            }
        }
    __syncthreads();
#pragma unroll
    for (int i = 0; i < 4; ++i) {
        int idx = i * 512 + t;
        keys[base + idx] = sk[idx];
    }
}

// ---------------- K3: merge top-512 (10 iters), decode, BITMASK NMS, top-128 -----
__global__ __launch_bounds__(256)
void k_nms(const unsigned long long* __restrict__ keys,
           const float* __restrict__ off_ws, float* __restrict__ out) {
    __shared__ unsigned long long top[512];
    __shared__ unsigned long long chk[512];
    __shared__ float bx1[512], by1[512], bx2[512], by2[512], bar[512], bsc[512];
    __shared__ int keep[512];
    __shared__ unsigned long long sup[512][9];   // 8 words + 1 pad (bank spread)
    __shared__ unsigned long long kmask[8];

    const int t = threadIdx.x;
    const int img = blockIdx.x;
    const size_t kbase = (size_t)img * NPAD;

    top[t] = keys[kbase + t];
    top[t + 256] = keys[kbase + t + 256];

    for (int c = 1; c < NCH2; ++c) {
        __syncthreads();
        chk[t] = keys[kbase + (size_t)c * CHSZ + t];
        chk[t + 256] = keys[kbase + (size_t)c * CHSZ + t + 256];
        __syncthreads();
        for (int i = t; i < 512; i += 256) {
            unsigned long long a = top[i], b = chk[511 - i];
            top[i] = (a > b) ? a : b;
        }
        for (int j = 256; j > 0; j >>= 1) {
            __syncthreads();
            int i = ((t & ~(j - 1)) << 1) | (t & (j - 1));
            unsigned long long a = top[i], b = top[i + j];
            if (a < b) { top[i] = b; top[i + j] = a; }
        }
    }
    __syncthreads();

    for (int i = t; i < 512; i += 256) {
        unsigned long long key = top[i];
        float s = __uint_as_float((unsigned)(key >> 32));
        unsigned id = 0xFFFFFFFFu - (unsigned)(key & 0xFFFFFFFFull);
        float x1 = 0.f, y1 = 0.f, x2 = 0.f, y2 = 0.f;
        bool valid = false;
        if (key != 0ull && id < (unsigned)NANCH) {
            int p = id / 9, a = id - p * 9;
            int gy = p / FMW, gx = p - gy * FMW;
            const double SS[3] = {32.0, 64.0, 128.0};
            const double RR[3] = {0.5, 1.0, 2.0};
            double sq = sqrt(RR[a % 3]);
            float wa32 = (float)(SS[a / 3] / sq);
            float ha32 = (float)(SS[a / 3] * sq);
            double cx = ((double)gx + 0.5) * 16.0;
            double cy = ((double)gy + 0.5) * 16.0;
            float ax1 = (float)(cx - (double)(wa32 * 0.5f));
            float ay1 = (float)(cy - (double)(ha32 * 0.5f));
            float ax2 = (float)(cx + (double)(wa32 * 0.5f));
            float ay2 = (float)(cy + (double)(ha32 * 0.5f));
            float aw = ax2 - ax1, ah2 = ay2 - ay1;
            float acx = ax1 + 0.5f * aw, acy = ay1 + 0.5f * ah2;
            const float4 off = *(const float4*)(off_ws + ((size_t)img * P_IMG + p) * 36 + a * 4);
            float px = acx + off.x * aw;
            float py = acy + off.y * ah2;
            float pw = aw * expf(off.z);
            float ph = ah2 * expf(off.w);
            x1 = fminf(fmaxf(px - 0.5f * pw, 0.f), 800.f);
            y1 = fminf(fmaxf(py - 0.5f * ph, 0.f), 800.f);
            x2 = fminf(fmaxf(px + 0.5f * pw, 0.f), 800.f);
            y2 = fminf(fmaxf(py + 0.5f * ph, 0.f), 800.f);
            float ww = x2 - x1, hh = y2 - y1;
            valid = (ww >= 1e-3f) && (hh >= 1e-3f) && (s >= 0.5f);
        }
        bx1[i] = x1; by1[i] = y1; bx2[i] = x2; by2[i] = y2;
        bar[i] = (x2 - x1) * (y2 - y1);
        bsc[i] = s;
        keep[i] = valid ? 1 : 0;
    }
    __syncthreads();

    // ---- build suppression bit-matrix: sup[i] bit j = (iou>0.7) && (j>i) ----
    for (int i = t; i < 512; i += 256) {
        float xi1 = bx1[i], yi1 = by1[i], xi2 = bx2[i], yi2 = by2[i], ai = bar[i];
#pragma unroll
        for (int wd = 0; wd < 8; ++wd) {
            unsigned long long bits = 0ull;
            for (int b = 0; b < 64; ++b) {
                int j = wd * 64 + b;
                float lx = fmaxf(xi1, bx1[j]);
                float ly = fmaxf(yi1, by1[j]);
                float rx = fminf(xi2, bx2[j]);
                float ry = fminf(yi2, by2[j]);
                float iw = fmaxf(rx - lx, 0.f);
                float ih = fmaxf(ry - ly, 0.f);
                float inter = iw * ih;
                float iou = inter / (ai + bar[j] - inter + 1e-9f);
                if ((iou > 0.7f) && (j > i)) bits |= (1ull << b);
            }
            sup[i][wd] = bits;
        }
    }
    // pack initial keep mask (8 threads x 64 flags)
    if (t < 8) {
        unsigned long long m = 0ull;
#pragma unroll
        for (int b = 0; b < 64; ++b)
            if (keep[t * 64 + b]) m |= (1ull << b);
        kmask[t] = m;
    }
    __syncthreads();

    // ---- serial greedy sweep: one wave, zero barriers ----
    if (t < 64) {
        unsigned long long m = (t < 8) ? kmask[t] : 0ull;
        for (int i = 0; i < 512; ++i) {
            unsigned long long mw = __shfl(m, i >> 6);      // broadcast word i/64
            if ((mw >> (i & 63)) & 1ull) {                  // i still kept (uniform)
                if (t < 8) m &= ~sup[i][t];
            }
        }
        if (t < 8) kmask[t] = m;
    }
    __syncthreads();
    for (int i = t; i < 512; i += 256)
        keep[i] = (int)((kmask[i >> 6] >> (i & 63)) & 1ull);
    __syncthreads();

    for (int i = t; i < 512; i += 256) {
        float m = keep[i] ? bsc[i] : -1.0f;
        unsigned u = __float_as_uint(m);
        u = (u & 0x80000000u) ? ~u : (u | 0x80000000u);
        chk[i] = ((unsigned long long)u << 32) | (unsigned long long)(511 - i);
    }
    for (int k = 2; k <= 512; k <<= 1)
        for (int j = k >> 1; j > 0; j >>= 1) {
            __syncthreads();
            for (int i = t; i < 512; i += 256) {
                int lx = i ^ j;
                if (lx > i) {
                    unsigned long long a = chk[i], b = chk[lx];
                    bool desc = ((i & k) == 0);
                    if (desc ? (a < b) : (a > b)) { chk[i] = b; chk[lx] = a; }
                }
            }
        }
    __syncthreads();

    if (t < POST) {
        unsigned long long key = chk[t];
        int slot = 511 - (int)(key & 0xFFFFFFFFull);
        float m = keep[slot] ? bsc[slot] : -1.0f;
        bool ok = (m >= 0.5f);
        float* ob = out + ((size_t)img * POST + t) * 4;
        ob[0] = ok ? bx1[slot] : 0.f;
        ob[1] = ok ? by1[slot] : 0.f;
        ob[2] = ok ? bx2[slot] : 0.f;
        ob[3] = ok ? by2[slot] : 0.f;
        out[(size_t)BATCH * POST * 4 + img * POST + t] = ok ? m : 0.f;
    }
}

// ---------------- launcher ----------------
extern "C" void kernel_launch(void* const* d_in, const int* in_sizes, int n_in,
                              void* d_out, int out_size, void* d_ws, size_t ws_size,
                              hipStream_t stream) {
    const float* fm = (const float*)d_in[0];
    const float* w1 = (const float*)d_in[1];
    const float* b1 = (const float*)d_in[2];
    const float* w2 = (const float*)d_in[3];
    const float* b2 = (const float*)d_in[4];
    const float* w3 = (const float*)d_in[5];
    const float* b3 = (const float*)d_in[6];
    float* out = (float*)d_out;

    char* ws = (char*)d_ws;
    // ws layout (18,087,936 B — identical to V2's proven footprint):
    //   [0, 0x900000)           w1pack  (9,437,184 B)
    //   [0x900000, +5,760,000)  off_ws
    //   [0xE80000, +2,883,584)  keys
    char* w1pack = ws;
    float* off_ws = (float*)(ws + 0x900000);
    unsigned long long* keys = (unsigned long long*)(ws + 0xE80000);

    k_prepack<<<1152, 256, 0, stream>>>(w1, w1pack);
    k_conv_mfma<<<BATCH * NTIL, 512, 0, stream>>>(fm, w1pack, b1, w2, b2, w3, b3, off_ws, keys);
    k_sort_chunks<<<BATCH * NCH2, 512, 0, stream>>>(keys);
    k_nms<<<BATCH, 256, 0, stream>>>(keys, off_ws, out);
}